// Round 1
// baseline (284.885 us; speedup 1.0000x reference)
//
#include <hip/hip_runtime.h>

#define NN 100
#define EE 262144
#define NT 1024
#define PS 132   // LDS buffer P row stride (floats)
#define QS 260   // LDS buffer Q row stride (floats)
#define SP_CNT 8 // partial S copies (XCD-diluted atomics)
#define A_OFF 80000

// ---------------- edge scatter: S_part[dst][src] += ew ----------------
__global__ void scatter_kernel(const int* __restrict__ ei,
                               const float* __restrict__ ew,
                               float* __restrict__ Sbase) {
    int gid = blockIdx.x * blockDim.x + threadIdx.x;          // 0..65535
    float* S = Sbase + (blockIdx.x & (SP_CNT - 1)) * (NN * NN);
    int4   s4 = ((const int4*)ei)[gid];
    int4   d4 = ((const int4*)(ei + EE))[gid];
    float4 w4 = ((const float4*)ew)[gid];
    atomicAdd(&S[d4.x * NN + s4.x], w4.x);
    atomicAdd(&S[d4.y * NN + s4.y], w4.y);
    atomicAdd(&S[d4.z * NN + s4.z], w4.z);
    atomicAdd(&S[d4.w * NN + s4.w], w4.w);
}

// ---------------- build normalized adjacency A ----------------
__global__ void build_A_kernel(const float* __restrict__ S, float* __restrict__ A) {
    __shared__ float dinv[NN];
    int tid = threadIdx.x;
    if (tid < NN) {
        float deg = 1.0f;                       // self-loop weight 1
        for (int p = 0; p < SP_CNT; ++p) {
            const float* row = S + p * NN * NN + tid * NN;
            for (int s = 0; s < NN; ++s) deg += row[s];
        }
        dinv[tid] = rsqrtf(deg);
    }
    __syncthreads();
    for (int i = tid; i < NN * NN; i += blockDim.x) {
        int d = i / NN, s = i - d * NN;
        float sv = 0.f;
        for (int p = 0; p < SP_CNT; ++p) sv += S[p * NN * NN + i];
        float v = dinv[d] * dinv[s] * sv;
        if (d == s) v += dinv[d] * dinv[d];     // self-loop contribution
        A[i] = v;
    }
}

// ---------------- fused network (single block) ----------------
// g = A @ h, in place in LDS buffer (width Cpad, mult of 4), via reg staging
__device__ __forceinline__ void stage_g_inplace(float* buf, int stride, int Cpad,
                                                const float* __restrict__ A, int tid) {
    const int CT = Cpad >> 2;
    const int tiles = (NN >> 2) * CT;           // <= 800
    float acc[4][4];
    int n0 = 0, c0 = 0;
    const bool active = tid < tiles;
    if (active) {
        int nt = tid / CT;
        n0 = nt << 2;
        c0 = (tid - nt * CT) << 2;
#pragma unroll
        for (int r = 0; r < 4; ++r)
#pragma unroll
            for (int q = 0; q < 4; ++q) acc[r][q] = 0.f;
        const float* A0 = A + (n0 + 0) * NN;
        const float* A1 = A + (n0 + 1) * NN;
        const float* A2 = A + (n0 + 2) * NN;
        const float* A3 = A + (n0 + 3) * NN;
        for (int m = 0; m < NN; m += 4) {
            float4 a0 = *(const float4*)(A0 + m);
            float4 a1 = *(const float4*)(A1 + m);
            float4 a2 = *(const float4*)(A2 + m);
            float4 a3 = *(const float4*)(A3 + m);
            float4 h0 = *(const float4*)(buf + (m + 0) * stride + c0);
            float4 h1 = *(const float4*)(buf + (m + 1) * stride + c0);
            float4 h2 = *(const float4*)(buf + (m + 2) * stride + c0);
            float4 h3 = *(const float4*)(buf + (m + 3) * stride + c0);
#define GROW(r, ar) \
            acc[r][0] += ar.x*h0.x + ar.y*h1.x + ar.z*h2.x + ar.w*h3.x; \
            acc[r][1] += ar.x*h0.y + ar.y*h1.y + ar.z*h2.y + ar.w*h3.y; \
            acc[r][2] += ar.x*h0.z + ar.y*h1.z + ar.z*h2.z + ar.w*h3.z; \
            acc[r][3] += ar.x*h0.w + ar.y*h1.w + ar.z*h2.w + ar.w*h3.w;
            GROW(0, a0) GROW(1, a1) GROW(2, a2) GROW(3, a3)
#undef GROW
        }
    }
    __syncthreads();
    if (active) {
#pragma unroll
        for (int r = 0; r < 4; ++r) {
            float4 v = make_float4(acc[r][0], acc[r][1], acc[r][2], acc[r][3]);
            *(float4*)(buf + (n0 + r) * stride + c0) = v;
        }
    }
    __syncthreads();
}

// dst = relu(src @ W + b)   (src: [100][Cin] in LDS; W: [Cin][Cout] global)
__device__ __forceinline__ void stage_t(const float* src, int ss, int Cin,
                                        float* dst, int ds, int Cout,
                                        const float* __restrict__ W,
                                        const float* __restrict__ b, int tid) {
    const int JT = Cout >> 2;
    const int tiles = (NN >> 2) * JT;
    for (int t = tid; t < tiles; t += NT) {
        int nt = t / JT;
        int n0 = nt << 2;
        int j0 = (t - nt * JT) << 2;
        float acc[4][4];
#pragma unroll
        for (int r = 0; r < 4; ++r)
#pragma unroll
            for (int q = 0; q < 4; ++q) acc[r][q] = 0.f;
        int c = 0;
        for (; c + 4 <= Cin; c += 4) {
            float4 w0 = *(const float4*)(W + (c + 0) * Cout + j0);
            float4 w1 = *(const float4*)(W + (c + 1) * Cout + j0);
            float4 w2 = *(const float4*)(W + (c + 2) * Cout + j0);
            float4 w3 = *(const float4*)(W + (c + 3) * Cout + j0);
            float4 g0 = *(const float4*)(src + (n0 + 0) * ss + c);
            float4 g1 = *(const float4*)(src + (n0 + 1) * ss + c);
            float4 g2 = *(const float4*)(src + (n0 + 2) * ss + c);
            float4 g3 = *(const float4*)(src + (n0 + 3) * ss + c);
#define TROW(r, gr) \
            acc[r][0] += gr.x*w0.x + gr.y*w1.x + gr.z*w2.x + gr.w*w3.x; \
            acc[r][1] += gr.x*w0.y + gr.y*w1.y + gr.z*w2.y + gr.w*w3.y; \
            acc[r][2] += gr.x*w0.z + gr.y*w1.z + gr.z*w2.z + gr.w*w3.z; \
            acc[r][3] += gr.x*w0.w + gr.y*w1.w + gr.z*w2.w + gr.w*w3.w;
            TROW(0, g0) TROW(1, g1) TROW(2, g2) TROW(3, g3)
#undef TROW
        }
        for (; c < Cin; ++c) {                  // remainder (Cin=27)
            float4 wq = *(const float4*)(W + c * Cout + j0);
#pragma unroll
            for (int r = 0; r < 4; ++r) {
                float gv = src[(n0 + r) * ss + c];
                acc[r][0] += gv * wq.x;
                acc[r][1] += gv * wq.y;
                acc[r][2] += gv * wq.z;
                acc[r][3] += gv * wq.w;
            }
        }
        float4 bq = *(const float4*)(b + j0);
#pragma unroll
        for (int r = 0; r < 4; ++r) {
            float4 v;
            v.x = fmaxf(acc[r][0] + bq.x, 0.f);
            v.y = fmaxf(acc[r][1] + bq.y, 0.f);
            v.z = fmaxf(acc[r][2] + bq.z, 0.f);
            v.w = fmaxf(acc[r][3] + bq.w, 0.f);
            *(float4*)(dst + (n0 + r) * ds + j0) = v;
        }
    }
}

__global__ __launch_bounds__(NT) void fused_net_kernel(
    const float* __restrict__ x, const float* __restrict__ A,
    const float* __restrict__ W1, const float* __restrict__ b1,
    const float* __restrict__ W2, const float* __restrict__ b2,
    const float* __restrict__ W3, const float* __restrict__ b3,
    const float* __restrict__ gamma, const float* __restrict__ beta,
    const float* __restrict__ lw1, const float* __restrict__ lb1,
    const float* __restrict__ lw2, const float* __restrict__ lb2,
    float* __restrict__ out)
{
    __shared__ float P[NN * PS];       // 52.8 KB
    __shared__ float Q[NN * QS];       // 104 KB
    __shared__ float bnsc[256];
    __shared__ float bnsh[256];
    const int tid = threadIdx.x;

    // load x -> P (width 28, col 27 zero-padded)
    for (int i = tid; i < NN * 28; i += NT) {
        int n = i / 28, c = i - n * 28;
        P[n * PS + c] = (c < 27) ? x[n * 27 + c] : 0.f;
    }
    __syncthreads();

    stage_g_inplace(P, PS, 28, A, tid);                 // g1 = A@h0
    stage_t(P, PS, 27, Q, QS, 64, W1, b1, tid);         // h1 = relu(g1@W1+b1)
    __syncthreads();
    stage_g_inplace(Q, QS, 64, A, tid);                 // g2 = A@h1
    stage_t(Q, QS, 64, P, PS, 128, W2, b2, tid);        // h2
    __syncthreads();
    stage_g_inplace(P, PS, 128, A, tid);                // g3 = A@h2
    stage_t(P, PS, 128, Q, QS, 256, W3, b3, tid);       // h3 (in Q)
    __syncthreads();

    // BatchNorm (training-mode batch stats, biased var), thread-per-channel
    if (tid < 256) {
        float s = 0.f, s2 = 0.f;
        for (int n = 0; n < NN; ++n) {
            float v = Q[n * QS + tid];
            s += v; s2 += v * v;
        }
        float mu  = s * 0.01f;
        float var = s2 * 0.01f - mu * mu;
        float sc  = gamma[tid] * rsqrtf(var + 1e-5f);
        bnsc[tid] = sc;
        bnsh[tid] = beta[tid] - mu * sc;
    }
    __syncthreads();

    // lin1 (+BN inline) + relu -> y[1000] in P
    if (tid < 1000) {
        int n = tid / 10, k = tid - n * 10;
        const float* w  = lw1 + k * 256;
        const float* hr = Q + n * QS;
        float acc = lb1[k];
        for (int cc = 0; cc < 256; ++cc) {
            float v = hr[cc] * bnsc[cc] + bnsh[cc];
            acc += v * w[cc];
        }
        P[tid] = fmaxf(acc, 0.f);
    }
    __syncthreads();

    // lin2: out[j] = y @ lw2[j,:] + lb2[j], wave-per-output, coalesced lw2 rows
    const int wave = tid >> 6, lane = tid & 63;
    for (int j = wave; j < 128; j += 16) {
        const float* w = lw2 + j * 1000;
        float acc = 0.f;
        for (int i = lane; i < 1000; i += 64)
            acc += P[i] * w[i];
#pragma unroll
        for (int off = 32; off; off >>= 1)
            acc += __shfl_down(acc, off);
        if (lane == 0) out[j] = acc + lb2[j];
    }
}

extern "C" void kernel_launch(void* const* d_in, const int* in_sizes, int n_in,
                              void* d_out, int out_size, void* d_ws, size_t ws_size,
                              hipStream_t stream) {
    const float* x     = (const float*)d_in[0];
    const int*   ei    = (const int*)d_in[1];
    const float* ew    = (const float*)d_in[2];
    const float* W1    = (const float*)d_in[3];
    const float* b1    = (const float*)d_in[4];
    const float* W2    = (const float*)d_in[5];
    const float* b2    = (const float*)d_in[6];
    const float* W3    = (const float*)d_in[7];
    const float* b3    = (const float*)d_in[8];
    const float* gamma = (const float*)d_in[9];
    const float* beta  = (const float*)d_in[10];
    const float* lw1   = (const float*)d_in[11];
    const float* lb1   = (const float*)d_in[12];
    const float* lw2   = (const float*)d_in[13];
    const float* lb2   = (const float*)d_in[14];

    float* ws = (float*)d_ws;
    float* S  = ws;                 // 8 * 10000 floats
    float* A  = ws + A_OFF;         // 10000 floats
    float* out = (float*)d_out;

    hipMemsetAsync(S, 0, SP_CNT * NN * NN * sizeof(float), stream);
    scatter_kernel<<<EE / (256 * 4), 256, 0, stream>>>(ei, ew, S);
    build_A_kernel<<<1, 256, 0, stream>>>(S, A);
    fused_net_kernel<<<1, NT, 0, stream>>>(x, A, W1, b1, W2, b2, W3, b3,
                                           gamma, beta, lw1, lb1, lw2, lb2, out);
}

// Round 3
// 207.955 us; speedup vs baseline: 1.3699x; 1.3699x over previous
//
#include <hip/hip_runtime.h>

#define NN 100
#define EE 262144
#define SP_CNT 8

// ws layout (floats):
//   S  @ 0      : 80000  (8 partial copies, dead after buildA)
//   A  @ 80000  : 10000
//   h1 @ 0      : 6400   (reuses S region, written after S fully consumed)
//   h2 @ 6400   : 12800
//   h3 @ 19200  : 25600
#define WS_A  80000
#define WS_H1 0
#define WS_H2 6400
#define WS_H3 19200

// ---------------- edge scatter: S_part[dst][src] += ew ----------------
__global__ void scatter_kernel(const int* __restrict__ ei,
                               const float* __restrict__ ew,
                               float* __restrict__ Sbase) {
    int gid = blockIdx.x * blockDim.x + threadIdx.x;          // 0..65535
    float* S = Sbase + (blockIdx.x & (SP_CNT - 1)) * (NN * NN);
    int4   s4 = ((const int4*)ei)[gid];
    int4   d4 = ((const int4*)(ei + EE))[gid];
    float4 w4 = ((const float4*)ew)[gid];
    atomicAdd(&S[d4.x * NN + s4.x], w4.x);
    atomicAdd(&S[d4.y * NN + s4.y], w4.y);
    atomicAdd(&S[d4.z * NN + s4.z], w4.z);
    atomicAdd(&S[d4.w * NN + s4.w], w4.w);
}

// ---------------- build A (normalized adjacency) + layer 1, one block ----
__global__ __launch_bounds__(1024) void buildA_l1_kernel(
    const float* __restrict__ S, float* __restrict__ Aglob,
    const float* __restrict__ x, const float* __restrict__ W1,
    const float* __restrict__ b1, float* __restrict__ h1g)
{
    __shared__ float Al[NN * NN];        // 40 KB: first sumS, then A
    __shared__ float part[NN][4];
    __shared__ float dinv[NN];
    __shared__ float xl[NN * 28];        // x zero-padded to 28 cols
    __shared__ float g1[NN * 28];
    __shared__ float W1l[27 * 64];
    __shared__ float b1l[64];
    const int tid = threadIdx.x;

    // stage x, W1, b1 (independent of S)
    for (int i = tid; i < NN * 28; i += 1024) {
        int n = i / 28, c = i - n * 28;
        xl[i] = (c < 27) ? x[n * 27 + c] : 0.f;
    }
    for (int i = tid; i < 27 * 64; i += 1024) W1l[i] = W1[i];
    if (tid < 64) b1l[tid] = b1[tid];

    // sumS = sum over 8 partial copies (coalesced float4)
    for (int i = tid; i < 2500; i += 1024) {
        float4 a = ((const float4*)S)[i];
#pragma unroll
        for (int p = 1; p < SP_CNT; ++p) {
            float4 b = ((const float4*)S)[p * 2500 + i];
            a.x += b.x; a.y += b.y; a.z += b.z; a.w += b.w;
        }
        ((float4*)Al)[i] = a;
    }
    __syncthreads();

    // row degrees -> dinv
    if (tid < 400) {
        int row = tid >> 2, q = tid & 3;
        const float* r = Al + row * NN + q * 25;
        float s = 0.f;
#pragma unroll
        for (int k = 0; k < 25; ++k) s += r[k];
        part[row][q] = s;
    }
    __syncthreads();
    if (tid < NN)
        dinv[tid] = rsqrtf(1.f + part[tid][0] + part[tid][1] + part[tid][2] + part[tid][3]);
    __syncthreads();

    // A[d][s] = dinv[d]*sumS*dinv[s] (+ dinv^2 on diag), in place
    for (int i = tid; i < NN * NN; i += 1024) {
        int d = i / NN, s = i - d * NN;
        float v = dinv[d] * dinv[s] * Al[i];
        if (d == s) v += dinv[d] * dinv[d];
        Al[i] = v;
        Aglob[i] = v;
    }
    __syncthreads();

    // g1 = A @ x : 25 rowgroups x 7 colgroups, 4x4 register tiles (b128 LDS)
    if (tid < 175) {
        int nt = tid / 7, n0 = nt * 4, c0 = (tid - nt * 7) * 4;
        float acc[4][4];
#pragma unroll
        for (int r = 0; r < 4; ++r)
#pragma unroll
            for (int q = 0; q < 4; ++q) acc[r][q] = 0.f;
        for (int m = 0; m < NN; m += 4) {
            float4 a0 = *(const float4*)(Al + (n0 + 0) * NN + m);
            float4 a1 = *(const float4*)(Al + (n0 + 1) * NN + m);
            float4 a2 = *(const float4*)(Al + (n0 + 2) * NN + m);
            float4 a3 = *(const float4*)(Al + (n0 + 3) * NN + m);
            float4 x0 = *(const float4*)(xl + (m + 0) * 28 + c0);
            float4 x1 = *(const float4*)(xl + (m + 1) * 28 + c0);
            float4 x2 = *(const float4*)(xl + (m + 2) * 28 + c0);
            float4 x3 = *(const float4*)(xl + (m + 3) * 28 + c0);
#define GROW(r, ar) \
            acc[r][0] += ar.x*x0.x + ar.y*x1.x + ar.z*x2.x + ar.w*x3.x; \
            acc[r][1] += ar.x*x0.y + ar.y*x1.y + ar.z*x2.y + ar.w*x3.y; \
            acc[r][2] += ar.x*x0.z + ar.y*x1.z + ar.z*x2.z + ar.w*x3.z; \
            acc[r][3] += ar.x*x0.w + ar.y*x1.w + ar.z*x2.w + ar.w*x3.w;
            GROW(0, a0) GROW(1, a1) GROW(2, a2) GROW(3, a3)
#undef GROW
        }
#pragma unroll
        for (int r = 0; r < 4; ++r)
            *(float4*)(g1 + (n0 + r) * 28 + c0) =
                make_float4(acc[r][0], acc[r][1], acc[r][2], acc[r][3]);
    }
    __syncthreads();

    // h1 = relu(g1 @ W1 + b1): 25 rowgroups x 16 colgroups, 4x4 tiles
    if (tid < 400) {
        int nt = tid / 16, n0 = nt * 4, j0 = (tid - nt * 16) * 4;
        float acc[4][4];
#pragma unroll
        for (int r = 0; r < 4; ++r)
#pragma unroll
            for (int q = 0; q < 4; ++q) acc[r][q] = 0.f;
        for (int c = 0; c < 24; c += 4) {
            float4 w0 = *(const float4*)(W1l + (c + 0) * 64 + j0);
            float4 w1 = *(const float4*)(W1l + (c + 1) * 64 + j0);
            float4 w2 = *(const float4*)(W1l + (c + 2) * 64 + j0);
            float4 w3 = *(const float4*)(W1l + (c + 3) * 64 + j0);
            float4 g0 = *(const float4*)(g1 + (n0 + 0) * 28 + c);
            float4 g2_ = *(const float4*)(g1 + (n0 + 2) * 28 + c);
            float4 g1_ = *(const float4*)(g1 + (n0 + 1) * 28 + c);
            float4 g3_ = *(const float4*)(g1 + (n0 + 3) * 28 + c);
#define TROW(r, gr) \
            acc[r][0] += gr.x*w0.x + gr.y*w1.x + gr.z*w2.x + gr.w*w3.x; \
            acc[r][1] += gr.x*w0.y + gr.y*w1.y + gr.z*w2.y + gr.w*w3.y; \
            acc[r][2] += gr.x*w0.z + gr.y*w1.z + gr.z*w2.z + gr.w*w3.z; \
            acc[r][3] += gr.x*w0.w + gr.y*w1.w + gr.z*w2.w + gr.w*w3.w;
            TROW(0, g0) TROW(1, g1_) TROW(2, g2_) TROW(3, g3_)
#undef TROW
        }
#pragma unroll
        for (int c = 24; c < 27; ++c) {
            float4 wq = *(const float4*)(W1l + c * 64 + j0);
#pragma unroll
            for (int r = 0; r < 4; ++r) {
                float gv = g1[(n0 + r) * 28 + c];
                acc[r][0] += gv * wq.x; acc[r][1] += gv * wq.y;
                acc[r][2] += gv * wq.z; acc[r][3] += gv * wq.w;
            }
        }
        float4 bq = *(const float4*)(b1l + j0);      // <-- FIX: bias was dropped
#pragma unroll
        for (int r = 0; r < 4; ++r) {
            float4 v;
            v.x = fmaxf(acc[r][0] + bq.x, 0.f); v.y = fmaxf(acc[r][1] + bq.y, 0.f);
            v.z = fmaxf(acc[r][2] + bq.z, 0.f); v.w = fmaxf(acc[r][3] + bq.w, 0.f);
            *(float4*)(h1g + (n0 + r) * 64 + j0) = v;
        }
    }
}

// ---------------- layer 2: 50 blocks, 2 rows each ----------------
__global__ __launch_bounds__(256) void l2_kernel(
    const float* __restrict__ A, const float* __restrict__ h1,
    const float* __restrict__ W2, const float* __restrict__ b2,
    float* __restrict__ h2)
{
    __shared__ float h1l[NN * 64];
    __shared__ float Ar[2 * NN];
    __shared__ float g2[2 * 64];
    const int tid = threadIdx.x;
    const int n0 = blockIdx.x * 2;

    for (int i = tid; i < NN * 16; i += 256)
        ((float4*)h1l)[i] = ((const float4*)h1)[i];
    for (int i = tid; i < NN; i += 256) {
        Ar[i]      = A[(n0 + 0) * NN + i];
        Ar[NN + i] = A[(n0 + 1) * NN + i];
    }
    __syncthreads();

    if (tid < 128) {                         // g2[r][c], r<2, c<64
        int r = tid >> 6, c = tid & 63;
        const float* ar = Ar + r * NN;
        float acc = 0.f;
#pragma unroll 4
        for (int m = 0; m < NN; ++m) acc += ar[m] * h1l[m * 64 + c];
        g2[tid] = acc;
    }
    __syncthreads();

    {                                        // h2 row tile: 2x128, 1 out/thread
        int r = tid >> 7, j = tid & 127;
        const float* gr = g2 + r * 64;
        float acc = b2[j];
#pragma unroll 4
        for (int c = 0; c < 64; ++c) acc += gr[c] * W2[c * 128 + j];
        h2[(n0 + r) * 128 + j] = fmaxf(acc, 0.f);
    }
}

// ---------------- layer 3: 100 blocks, 1 row each ----------------
__global__ __launch_bounds__(256) void l3_kernel(
    const float* __restrict__ A, const float* __restrict__ h2,
    const float* __restrict__ W3, const float* __restrict__ b3,
    float* __restrict__ h3)
{
    __shared__ float h2l[NN * 128];
    __shared__ float Ar[NN];
    __shared__ float g3[128];
    const int tid = threadIdx.x;
    const int n = blockIdx.x;

    for (int i = tid; i < NN * 32; i += 256)
        ((float4*)h2l)[i] = ((const float4*)h2)[i];
    for (int i = tid; i < NN; i += 256) Ar[i] = A[n * NN + i];
    __syncthreads();

    if (tid < 128) {                         // g3[c]
        int c = tid;
        float acc = 0.f;
#pragma unroll 4
        for (int m = 0; m < NN; ++m) acc += Ar[m] * h2l[m * 128 + c];
        g3[c] = acc;
    }
    __syncthreads();

    {                                        // h3 row: 256 outs, 1/thread
        int j = tid;
        float acc = b3[j];
#pragma unroll 4
        for (int c = 0; c < 128; ++c) acc += g3[c] * W3[c * 256 + j];
        h3[n * 256 + j] = fmaxf(acc, 0.f);
    }
}

// ---------------- tail: BN + lin1 + relu + lin2, one block ----------------
#define HS 260
__global__ __launch_bounds__(1024) void tail_kernel(
    const float* __restrict__ h3, const float* __restrict__ gamma,
    const float* __restrict__ beta, const float* __restrict__ lw1,
    const float* __restrict__ lb1, const float* __restrict__ lw2,
    const float* __restrict__ lb2, float* __restrict__ out)
{
    __shared__ float h3l[NN * HS];           // 104 KB, stride 260 breaks conflicts
    __shared__ float y[1000];
    __shared__ float bnsc[256], bnsh[256];
    const int tid = threadIdx.x;

    for (int i = tid; i < NN * 64; i += 1024) {   // 6400 float4 loads
        int g = i * 4, n = g >> 8, c = g & 255;
        *(float4*)(h3l + n * HS + c) = ((const float4*)h3)[i];
    }
    __syncthreads();

    if (tid < 256) {                         // BN batch stats per channel
        float s = 0.f, s2 = 0.f;
        for (int n = 0; n < NN; ++n) {
            float v = h3l[n * HS + tid];
            s += v; s2 += v * v;
        }
        float mu  = s * 0.01f;
        float var = s2 * 0.01f - mu * mu;
        float sc  = gamma[tid] * rsqrtf(var + 1e-5f);
        bnsc[tid] = sc;
        bnsh[tid] = beta[tid] - mu * sc;
    }
    __syncthreads();

    if (tid < 1000) {                        // lin1 (+BN inline) + relu
        int n = tid / 10, k = tid - n * 10;
        const float* w  = lw1 + k * 256;
        const float* hr = h3l + n * HS;
        float acc = lb1[k];
#pragma unroll 4
        for (int c = 0; c < 256; ++c)
            acc += (hr[c] * bnsc[c] + bnsh[c]) * w[c];
        y[tid] = fmaxf(acc, 0.f);
    }
    __syncthreads();

    const int wave = tid >> 6, lane = tid & 63;   // lin2: wave per output
    for (int j = wave; j < 128; j += 16) {
        const float* w = lw2 + j * 1000;
        float acc = 0.f;
        for (int i = lane; i < 1000; i += 64) acc += y[i] * w[i];
#pragma unroll
        for (int off = 32; off; off >>= 1) acc += __shfl_down(acc, off);
        if (lane == 0) out[j] = acc + lb2[j];
    }
}

extern "C" void kernel_launch(void* const* d_in, const int* in_sizes, int n_in,
                              void* d_out, int out_size, void* d_ws, size_t ws_size,
                              hipStream_t stream) {
    const float* x     = (const float*)d_in[0];
    const int*   ei    = (const int*)d_in[1];
    const float* ew    = (const float*)d_in[2];
    const float* W1    = (const float*)d_in[3];
    const float* b1    = (const float*)d_in[4];
    const float* W2    = (const float*)d_in[5];
    const float* b2    = (const float*)d_in[6];
    const float* W3    = (const float*)d_in[7];
    const float* b3    = (const float*)d_in[8];
    const float* gamma = (const float*)d_in[9];
    const float* beta  = (const float*)d_in[10];
    const float* lw1   = (const float*)d_in[11];
    const float* lb1   = (const float*)d_in[12];
    const float* lw2   = (const float*)d_in[13];
    const float* lb2   = (const float*)d_in[14];

    float* ws = (float*)d_ws;
    float* S  = ws;
    float* A  = ws + WS_A;
    float* h1 = ws + WS_H1;
    float* h2 = ws + WS_H2;
    float* h3 = ws + WS_H3;
    float* out = (float*)d_out;

    hipMemsetAsync(S, 0, SP_CNT * NN * NN * sizeof(float), stream);
    scatter_kernel<<<EE / (256 * 4), 256, 0, stream>>>(ei, ew, S);
    buildA_l1_kernel<<<1, 1024, 0, stream>>>(S, A, x, W1, b1, h1);
    l2_kernel<<<50, 256, 0, stream>>>(A, h1, W2, b2, h2);
    l3_kernel<<<100, 256, 0, stream>>>(A, h2, W3, b3, h3);
    tail_kernel<<<1, 1024, 0, stream>>>(h3, gamma, beta, lw1, lb1, lw2, lb2, out);
}

// Round 4
// 142.880 us; speedup vs baseline: 1.9939x; 1.4555x over previous
//
#include <hip/hip_runtime.h>

#define NN 100
#define EE 262144
#define SP_CNT 8

// ws layout (floats):
//   S  @ 0      : 80000  (8 partial copies; dead after buildA)
//   MS @ 80000  : 512    (BN sum[256], sumsq[256]; zeroed with S by one memset)
//   A  @ 80512  : 10000
//   h1 @ 0      : 6400   (reuses dead S region)
//   h2 @ 6400   : 12800
//   h3 @ 19200  : 25600
//   y  @ 44800  : 1000
#define WS_MS 80000
#define WS_A  80512
#define WS_H1 0
#define WS_H2 6400
#define WS_H3 19200
#define WS_Y  44800

// ---------------- edge scatter: S_part[dst][src] += ew ----------------
__global__ __launch_bounds__(256) void scatter_kernel(
    const int* __restrict__ ei, const float* __restrict__ ew,
    float* __restrict__ Sbase) {
    int gid = blockIdx.x * blockDim.x + threadIdx.x;          // 0..65535
    float* S = Sbase + (blockIdx.x & (SP_CNT - 1)) * (NN * NN);
    int4   s4 = ((const int4*)ei)[gid];
    int4   d4 = ((const int4*)(ei + EE))[gid];
    float4 w4 = ((const float4*)ew)[gid];
    atomicAdd(&S[d4.x * NN + s4.x], w4.x);
    atomicAdd(&S[d4.y * NN + s4.y], w4.y);
    atomicAdd(&S[d4.z * NN + s4.z], w4.z);
    atomicAdd(&S[d4.w * NN + s4.w], w4.w);
}

// ---------------- build A (normalized adjacency) + layer 1, one block ----
__global__ __launch_bounds__(1024) void buildA_l1_kernel(
    const float* __restrict__ S, float* __restrict__ Aglob,
    const float* __restrict__ x, const float* __restrict__ W1,
    const float* __restrict__ b1, float* __restrict__ h1g)
{
    __shared__ float Al[NN * NN];        // 40 KB: first sumS, then A
    __shared__ float part[NN][4];
    __shared__ float dinv[NN];
    __shared__ float xl[NN * 28];        // x zero-padded to 28 cols
    __shared__ float g1[NN * 28];
    __shared__ float W1l[27 * 64];
    __shared__ float b1l[64];
    const int tid = threadIdx.x;

    // stage x, W1, b1 (independent of S)
    for (int i = tid; i < NN * 28; i += 1024) {
        int n = i / 28, c = i - n * 28;
        xl[i] = (c < 27) ? x[n * 27 + c] : 0.f;
    }
    for (int i = tid; i < 27 * 64; i += 1024) W1l[i] = W1[i];
    if (tid < 64) b1l[tid] = b1[tid];

    // sumS = sum over 8 partial copies (coalesced float4)
    for (int i = tid; i < 2500; i += 1024) {
        float4 a = ((const float4*)S)[i];
#pragma unroll
        for (int p = 1; p < SP_CNT; ++p) {
            float4 b = ((const float4*)S)[p * 2500 + i];
            a.x += b.x; a.y += b.y; a.z += b.z; a.w += b.w;
        }
        ((float4*)Al)[i] = a;
    }
    __syncthreads();

    // row degrees -> dinv
    if (tid < 400) {
        int row = tid >> 2, q = tid & 3;
        const float* r = Al + row * NN + q * 25;
        float s = 0.f;
#pragma unroll
        for (int k = 0; k < 25; ++k) s += r[k];
        part[row][q] = s;
    }
    __syncthreads();
    if (tid < NN)
        dinv[tid] = rsqrtf(1.f + part[tid][0] + part[tid][1] + part[tid][2] + part[tid][3]);
    __syncthreads();

    // A[d][s] = dinv[d]*sumS*dinv[s] (+ dinv^2 on diag), in place
    for (int i = tid; i < NN * NN; i += 1024) {
        int d = i / NN, s = i - d * NN;
        float v = dinv[d] * dinv[s] * Al[i];
        if (d == s) v += dinv[d] * dinv[d];
        Al[i] = v;
        Aglob[i] = v;
    }
    __syncthreads();

    // g1 = A @ x : 25 rowgroups x 7 colgroups, 4x4 register tiles
    if (tid < 175) {
        int nt = tid / 7, n0 = nt * 4, c0 = (tid - nt * 7) * 4;
        float acc[4][4];
#pragma unroll
        for (int r = 0; r < 4; ++r)
#pragma unroll
            for (int q = 0; q < 4; ++q) acc[r][q] = 0.f;
        for (int m = 0; m < NN; m += 4) {
            float4 a0 = *(const float4*)(Al + (n0 + 0) * NN + m);
            float4 a1 = *(const float4*)(Al + (n0 + 1) * NN + m);
            float4 a2 = *(const float4*)(Al + (n0 + 2) * NN + m);
            float4 a3 = *(const float4*)(Al + (n0 + 3) * NN + m);
            float4 x0 = *(const float4*)(xl + (m + 0) * 28 + c0);
            float4 x1 = *(const float4*)(xl + (m + 1) * 28 + c0);
            float4 x2 = *(const float4*)(xl + (m + 2) * 28 + c0);
            float4 x3 = *(const float4*)(xl + (m + 3) * 28 + c0);
#define GROW(r, ar) \
            acc[r][0] += ar.x*x0.x + ar.y*x1.x + ar.z*x2.x + ar.w*x3.x; \
            acc[r][1] += ar.x*x0.y + ar.y*x1.y + ar.z*x2.y + ar.w*x3.y; \
            acc[r][2] += ar.x*x0.z + ar.y*x1.z + ar.z*x2.z + ar.w*x3.z; \
            acc[r][3] += ar.x*x0.w + ar.y*x1.w + ar.z*x2.w + ar.w*x3.w;
            GROW(0, a0) GROW(1, a1) GROW(2, a2) GROW(3, a3)
#undef GROW
        }
#pragma unroll
        for (int r = 0; r < 4; ++r)
            *(float4*)(g1 + (n0 + r) * 28 + c0) =
                make_float4(acc[r][0], acc[r][1], acc[r][2], acc[r][3]);
    }
    __syncthreads();

    // h1 = relu(g1 @ W1 + b1): 25 rowgroups x 16 colgroups, 4x4 tiles
    if (tid < 400) {
        int nt = tid / 16, n0 = nt * 4, j0 = (tid - nt * 16) * 4;
        float acc[4][4];
#pragma unroll
        for (int r = 0; r < 4; ++r)
#pragma unroll
            for (int q = 0; q < 4; ++q) acc[r][q] = 0.f;
        for (int c = 0; c < 24; c += 4) {
            float4 w0 = *(const float4*)(W1l + (c + 0) * 64 + j0);
            float4 w1 = *(const float4*)(W1l + (c + 1) * 64 + j0);
            float4 w2 = *(const float4*)(W1l + (c + 2) * 64 + j0);
            float4 w3 = *(const float4*)(W1l + (c + 3) * 64 + j0);
            float4 g0 = *(const float4*)(g1 + (n0 + 0) * 28 + c);
            float4 g2_ = *(const float4*)(g1 + (n0 + 2) * 28 + c);
            float4 g1_ = *(const float4*)(g1 + (n0 + 1) * 28 + c);
            float4 g3_ = *(const float4*)(g1 + (n0 + 3) * 28 + c);
#define TROW(r, gr) \
            acc[r][0] += gr.x*w0.x + gr.y*w1.x + gr.z*w2.x + gr.w*w3.x; \
            acc[r][1] += gr.x*w0.y + gr.y*w1.y + gr.z*w2.y + gr.w*w3.y; \
            acc[r][2] += gr.x*w0.z + gr.y*w1.z + gr.z*w2.z + gr.w*w3.z; \
            acc[r][3] += gr.x*w0.w + gr.y*w1.w + gr.z*w2.w + gr.w*w3.w;
            TROW(0, g0) TROW(1, g1_) TROW(2, g2_) TROW(3, g3_)
#undef TROW
        }
#pragma unroll
        for (int c = 24; c < 27; ++c) {
            float4 wq = *(const float4*)(W1l + c * 64 + j0);
#pragma unroll
            for (int r = 0; r < 4; ++r) {
                float gv = g1[(n0 + r) * 28 + c];
                acc[r][0] += gv * wq.x; acc[r][1] += gv * wq.y;
                acc[r][2] += gv * wq.z; acc[r][3] += gv * wq.w;
            }
        }
        float4 bq = *(const float4*)(b1l + j0);
#pragma unroll
        for (int r = 0; r < 4; ++r) {
            float4 v;
            v.x = fmaxf(acc[r][0] + bq.x, 0.f); v.y = fmaxf(acc[r][1] + bq.y, 0.f);
            v.z = fmaxf(acc[r][2] + bq.z, 0.f); v.w = fmaxf(acc[r][3] + bq.w, 0.f);
            *(float4*)(h1g + (n0 + r) * 64 + j0) = v;
        }
    }
}

// ---------------- layer 2: 50 blocks, 2 rows each ----------------
__global__ __launch_bounds__(256) void l2_kernel(
    const float* __restrict__ A, const float* __restrict__ h1,
    const float* __restrict__ W2, const float* __restrict__ b2,
    float* __restrict__ h2)
{
    __shared__ float h1l[NN * 64];
    __shared__ float Ar[2 * NN];
    __shared__ float g2[2 * 64];
    const int tid = threadIdx.x;
    const int n0 = blockIdx.x * 2;

    for (int i = tid; i < NN * 16; i += 256)
        ((float4*)h1l)[i] = ((const float4*)h1)[i];
    for (int i = tid; i < NN; i += 256) {
        Ar[i]      = A[(n0 + 0) * NN + i];
        Ar[NN + i] = A[(n0 + 1) * NN + i];
    }
    __syncthreads();

    if (tid < 128) {                         // g2[r][c], r<2, c<64
        int r = tid >> 6, c = tid & 63;
        const float* ar = Ar + r * NN;
        float acc = 0.f;
#pragma unroll 4
        for (int m = 0; m < NN; ++m) acc += ar[m] * h1l[m * 64 + c];
        g2[tid] = acc;
    }
    __syncthreads();

    {                                        // h2 row tile: 2x128, 1 out/thread
        int r = tid >> 7, j = tid & 127;
        const float* gr = g2 + r * 64;
        float acc = b2[j];
#pragma unroll 4
        for (int c = 0; c < 64; ++c) acc += gr[c] * W2[c * 128 + j];
        h2[(n0 + r) * 128 + j] = fmaxf(acc, 0.f);
    }
}

// ---------------- layer 3 + BN-stat accumulation: 100 blocks ----------------
__global__ __launch_bounds__(256) void l3_kernel(
    const float* __restrict__ A, const float* __restrict__ h2,
    const float* __restrict__ W3, const float* __restrict__ b3,
    float* __restrict__ h3, float* __restrict__ ms)   // ms: sum[256], sumsq[256]
{
    __shared__ float h2l[NN * 128];
    __shared__ float Ar[NN];
    __shared__ float g3[128];
    const int tid = threadIdx.x;
    const int n = blockIdx.x;

    for (int i = tid; i < NN * 32; i += 256)
        ((float4*)h2l)[i] = ((const float4*)h2)[i];
    for (int i = tid; i < NN; i += 256) Ar[i] = A[n * NN + i];
    __syncthreads();

    if (tid < 128) {                         // g3[c]
        int c = tid;
        float acc = 0.f;
#pragma unroll 4
        for (int m = 0; m < NN; ++m) acc += Ar[m] * h2l[m * 128 + c];
        g3[c] = acc;
    }
    __syncthreads();

    {                                        // h3 row: 256 outs, 1/thread
        int j = tid;
        float acc = b3[j];
#pragma unroll 4
        for (int c = 0; c < 128; ++c) acc += g3[c] * W3[c * 256 + j];
        float v = fmaxf(acc, 0.f);
        h3[n * 256 + j] = v;
        atomicAdd(&ms[j], v);                // BN column sum
        atomicAdd(&ms[256 + j], v * v);      // BN column sumsq
    }
}

// ---------------- lin1 (+BN apply): 100 blocks x 1 wave ----------------
__global__ __launch_bounds__(64) void lin1_kernel(
    const float* __restrict__ h3, const float* __restrict__ ms,
    const float* __restrict__ gamma, const float* __restrict__ beta,
    const float* __restrict__ lw1, const float* __restrict__ lb1,
    float* __restrict__ y)
{
    __shared__ float v[256];                 // BN-applied h3 row
    const int lane = threadIdx.x;
    const int n = blockIdx.x;

    {   // 4 channels per lane: v[c] = h3[n,c]*sc + sh
        int c0 = lane * 4;
        float4 h = *(const float4*)(h3 + n * 256 + c0);
        float4 s1 = *(const float4*)(ms + c0);          // sums
        float4 s2 = *(const float4*)(ms + 256 + c0);    // sumsqs
        float4 gm = *(const float4*)(gamma + c0);
        float4 bt = *(const float4*)(beta + c0);
        float4 r;
#define BNAP(f) { \
        float mu = s1.f * 0.01f; \
        float var = s2.f * 0.01f - mu * mu; \
        float sc = gm.f * rsqrtf(var + 1e-5f); \
        r.f = h.f * sc + (bt.f - mu * sc); }
        BNAP(x) BNAP(y) BNAP(z) BNAP(w)
#undef BNAP
        *(float4*)(v + c0) = r;
    }
    __syncthreads();

    const int c0 = lane * 4;
    float4 hv = *(const float4*)(v + c0);    // per-lane slice, reused for all k
#pragma unroll
    for (int k = 0; k < 10; ++k) {
        float4 w = *(const float4*)(lw1 + k * 256 + c0);
        float acc = hv.x * w.x + hv.y * w.y + hv.z * w.z + hv.w * w.w;
#pragma unroll
        for (int off = 32; off; off >>= 1) acc += __shfl_down(acc, off);
        if (lane == 0) y[n * 10 + k] = fmaxf(acc + lb1[k], 0.f);
    }
}

// ---------------- lin2: 128 blocks x 1 wave ----------------
__global__ __launch_bounds__(64) void lin2_kernel(
    const float* __restrict__ y, const float* __restrict__ lw2,
    const float* __restrict__ lb2, float* __restrict__ out)
{
    const int lane = threadIdx.x;
    const int j = blockIdx.x;
    const float4* y4 = (const float4*)y;            // 250 float4
    const float4* w4 = (const float4*)(lw2 + j * 1000);
    float acc = 0.f;
#pragma unroll
    for (int i = lane; i < 250; i += 64) {          // up to 4 independent float4 pairs
        float4 a = y4[i], b = w4[i];
        acc += a.x * b.x + a.y * b.y + a.z * b.z + a.w * b.w;
    }
#pragma unroll
    for (int off = 32; off; off >>= 1) acc += __shfl_down(acc, off);
    if (lane == 0) out[j] = acc + lb2[j];
}

extern "C" void kernel_launch(void* const* d_in, const int* in_sizes, int n_in,
                              void* d_out, int out_size, void* d_ws, size_t ws_size,
                              hipStream_t stream) {
    const float* x     = (const float*)d_in[0];
    const int*   ei    = (const int*)d_in[1];
    const float* ew    = (const float*)d_in[2];
    const float* W1    = (const float*)d_in[3];
    const float* b1    = (const float*)d_in[4];
    const float* W2    = (const float*)d_in[5];
    const float* b2    = (const float*)d_in[6];
    const float* W3    = (const float*)d_in[7];
    const float* b3    = (const float*)d_in[8];
    const float* gamma = (const float*)d_in[9];
    const float* beta  = (const float*)d_in[10];
    const float* lw1   = (const float*)d_in[11];
    const float* lb1   = (const float*)d_in[12];
    const float* lw2   = (const float*)d_in[13];
    const float* lb2   = (const float*)d_in[14];

    float* ws = (float*)d_ws;
    float* S  = ws;
    float* MS = ws + WS_MS;
    float* A  = ws + WS_A;
    float* h1 = ws + WS_H1;
    float* h2 = ws + WS_H2;
    float* h3 = ws + WS_H3;
    float* y  = ws + WS_Y;
    float* out = (float*)d_out;

    // zero S (8 copies) + MS (BN sums) in one memset
    hipMemsetAsync(S, 0, (SP_CNT * NN * NN + 512) * sizeof(float), stream);
    scatter_kernel<<<EE / (256 * 4), 256, 0, stream>>>(ei, ew, S);
    buildA_l1_kernel<<<1, 1024, 0, stream>>>(S, A, x, W1, b1, h1);
    l2_kernel<<<50, 256, 0, stream>>>(A, h1, W2, b2, h2);
    l3_kernel<<<100, 256, 0, stream>>>(A, h2, W3, b3, h3, MS);
    lin1_kernel<<<100, 64, 0, stream>>>(h3, MS, gamma, beta, lw1, lb1, y);
    lin2_kernel<<<128, 64, 0, stream>>>(y, lw2, lb2, out);
}